// Round 4
// baseline (605.427 us; speedup 1.0000x reference)
//
#include <hip/hip_runtime.h>
#include <math.h>

// ---------------------------------------------------------------------------
// GCN 2-layer: h1 = relu(gcnconv(x,W1,b1)); out = log_softmax(gcnconv(h1,W2,b2))
// R10: (a) edge records shrunk 8B->4B (src only; agg gathers dinv[src] from
//      the L2-resident 400KB table) -> build scatter region halves (better L2
//      residency, less write-allocate), agg sEdge stream halves;
//      (b) agg cross-edge reduce via single LDS transpose (stride-68 pad,
//      balanced banks): 27 DS-ops/wave -> 10, -17 VALU;
//      (c) dinv folded into scan1; w1t+w2split merged (12 -> 10 dispatches).
// Structure from R9: out = log_softmax( agg2(relu(agg1(x@W1)+b1)) @ W2 + b2 )
// (layer-2 linear map hoisted out of per-node epilogue by linearity);
// gemm1/gemm2sm via bf16 MFMA; gemm2 W2 split hi/lo bf16 for ~f32 accuracy.
// N=100000, E=1600000, F: 512 -> 64 -> 40
// ---------------------------------------------------------------------------

#define FIN 512
#define FHID 64
#define FOUT 40

typedef __attribute__((ext_vector_type(8))) short short8;
typedef __attribute__((ext_vector_type(4))) float f32x4;
typedef unsigned short ushort_t;
typedef unsigned int uint_t;

__device__ __forceinline__ ushort_t bf16_rn(float f) {
    union { float f; uint_t u; } v; v.f = f;
    uint_t r = v.u + 0x7FFF + ((v.u >> 16) & 1);
    return (ushort_t)(r >> 16);
}
__device__ __forceinline__ uint_t pack_bf16(float a, float b) {
    return (uint_t)bf16_rn(a) | ((uint_t)bf16_rn(b) << 16);
}
__device__ __forceinline__ float bf16_to_f(ushort_t u) {
    union { uint_t i; float f; } t; t.i = ((uint_t)u) << 16; return t.f;
}
// accumulate 8 bf16 feats (one uint4) * nm into acc[8]
__device__ __forceinline__ void acc8(float* acc, uint4 g, float nm) {
    acc[0] = fmaf(__uint_as_float(g.x << 16), nm, acc[0]);
    acc[1] = fmaf(__uint_as_float(g.x & 0xFFFF0000u), nm, acc[1]);
    acc[2] = fmaf(__uint_as_float(g.y << 16), nm, acc[2]);
    acc[3] = fmaf(__uint_as_float(g.y & 0xFFFF0000u), nm, acc[3]);
    acc[4] = fmaf(__uint_as_float(g.z << 16), nm, acc[4]);
    acc[5] = fmaf(__uint_as_float(g.z & 0xFFFF0000u), nm, acc[5]);
    acc[6] = fmaf(__uint_as_float(g.w << 16), nm, acc[6]);
    acc[7] = fmaf(__uint_as_float(g.w & 0xFFFF0000u), nm, acc[7]);
}

// ---------------- histogram of in-degree (x4 vectorized) ----------------
__global__ void hist_kernel(const int* __restrict__ col, int* __restrict__ deg, int E) {
    int i = (blockIdx.x * 256 + threadIdx.x) * 4;
    if (i + 3 < E) {
        int4 c = *reinterpret_cast<const int4*>(&col[i]);
        atomicAdd(&deg[c.x], 1); atomicAdd(&deg[c.y], 1);
        atomicAdd(&deg[c.z], 1); atomicAdd(&deg[c.w], 1);
    } else {
        for (int j = i; j < E; ++j) atomicAdd(&deg[col[j]], 1);
    }
}

// ---------------- scan (block-local) + dinv fold ----------------
__global__ void scan1_kernel(const int* __restrict__ deg, int* __restrict__ offs,
                             int* __restrict__ bsums, float* __restrict__ dinv, int n) {
    __shared__ int tmp[256];
    int tid = threadIdx.x;
    int i = blockIdx.x * 256 + tid;
    int v = (i < n) ? deg[i] : 0;
    if (i < n) dinv[i] = rsqrtf((float)v + 1.0f);
    tmp[tid] = v;
    __syncthreads();
    for (int off = 1; off < 256; off <<= 1) {
        int t = (tid >= off) ? tmp[tid - off] : 0;
        __syncthreads();
        tmp[tid] += t;
        __syncthreads();
    }
    if (i < n) offs[i] = tmp[tid] - v;
    if (tid == 255) bsums[blockIdx.x] = tmp[255];
}

__global__ void scan2_kernel(int* __restrict__ bsums, int nb) {
    __shared__ int tmp[512];
    int tid = threadIdx.x;
    int v = (tid < nb) ? bsums[tid] : 0;
    tmp[tid] = v;
    __syncthreads();
    for (int off = 1; off < 512; off <<= 1) {
        int t = (tid >= off) ? tmp[tid - off] : 0;
        __syncthreads();
        tmp[tid] += t;
        __syncthreads();
    }
    if (tid < nb) bsums[tid] = tmp[tid] - v;
}

__global__ void scan3_kernel(int* __restrict__ offs, const int* __restrict__ bsums,
                             int* __restrict__ cursor, int n) {
    int i = blockIdx.x * 256 + threadIdx.x;
    if (i < n) {
        int o = offs[i] + bsums[blockIdx.x];
        offs[i] = o;
        cursor[i] = o;
    }
}

// ---------------- build dest-sorted source list (4B records) ----------------
__global__ void build_kernel(const int* __restrict__ row, const int* __restrict__ col,
                             int* __restrict__ cursor, int* __restrict__ sSrc, int E) {
    int e = blockIdx.x * 256 + threadIdx.x;
    if (e < E) {
        int r = row[e], c = col[e];
        int pos = atomicAdd(&cursor[c], 1);
        sSrc[pos] = r;
    }
}

// ---------------- weights prep: W1^T bf16 + W2^T hi/lo bf16 split ----------
// Wt: [64][512] bf16. w2hi/w2lo: [48][64] bf16, rows 40..47 zero.
__global__ void wprep_kernel(const float* __restrict__ W1, const float* __restrict__ W2,
                             ushort_t* __restrict__ Wt,
                             ushort_t* __restrict__ w2hi, ushort_t* __restrict__ w2lo) {
    int idx = blockIdx.x * 256 + threadIdx.x;   // 35840 = 32768 + 3072
    if (idx < 32768) {
        int nrow = idx >> 9;
        int k = idx & 511;
        Wt[idx] = bf16_rn(W1[k * 64 + nrow]);
    } else if (idx < 32768 + 3072) {
        int i = idx - 32768;
        int j = i >> 6, k = i & 63;
        float w = (j < FOUT) ? W2[k * FOUT + j] : 0.f;
        ushort_t h = bf16_rn(w);
        w2hi[i] = h;
        w2lo[i] = bf16_rn(w - bf16_to_f(h));
    }
}

// ---------------- GEMM1 (MFMA): h1b[N,64] = bf16( x[N,512] @ W1[512,64] ) ----
// register-prefetch pipeline (single LDS buffer).
#define LDA 72
#define LDB 72
__global__ __launch_bounds__(256) void gemm1_kernel(
    const float* __restrict__ x, const ushort_t* __restrict__ Wt,
    ushort_t* __restrict__ h1b, int n) {
    __shared__ ushort_t lA[128 * LDA];
    __shared__ ushort_t lB[64 * LDB];

    int tid = threadIdx.x;
    int wave = tid >> 6, lane = tid & 63;
    int quad = lane >> 4, m16 = lane & 15;
    int node0 = blockIdx.x * 128;

    int r0 = tid >> 4, k4 = tid & 15;    // A: rows r0+16i, 16B at col k4*4
    int nr0 = tid >> 3, seg = tid & 7;   // B: rows nr0+32i, 16B at col seg*8

    f32x4 zero = {0.f, 0.f, 0.f, 0.f};
    f32x4 acc[2][4];
#pragma unroll
    for (int mt = 0; mt < 2; ++mt)
#pragma unroll
        for (int nt = 0; nt < 4; ++nt) acc[mt][nt] = zero;

    float4 ra[8];
    uint4 rb[2];

#pragma unroll
    for (int i = 0; i < 8; ++i) {
        int node = node0 + r0 + i * 16;
        float4 v = make_float4(0.f, 0.f, 0.f, 0.f);
        if (node < n) v = *reinterpret_cast<const float4*>(&x[(size_t)node * FIN + k4 * 4]);
        ra[i] = v;
    }
#pragma unroll
    for (int i = 0; i < 2; ++i)
        rb[i] = *reinterpret_cast<const uint4*>(&Wt[(size_t)(nr0 + i * 32) * FIN + seg * 8]);

    for (int c = 0; c < 8; ++c) {
#pragma unroll
        for (int i = 0; i < 8; ++i)
            *reinterpret_cast<uint2*>(&lA[(r0 + i * 16) * LDA + k4 * 4]) =
                make_uint2(pack_bf16(ra[i].x, ra[i].y), pack_bf16(ra[i].z, ra[i].w));
#pragma unroll
        for (int i = 0; i < 2; ++i)
            *reinterpret_cast<uint4*>(&lB[(nr0 + i * 32) * LDB + seg * 8]) = rb[i];
        __syncthreads();

        if (c < 7) {
            int kc = (c + 1) * 64;
#pragma unroll
            for (int i = 0; i < 8; ++i) {
                int node = node0 + r0 + i * 16;
                float4 v = make_float4(0.f, 0.f, 0.f, 0.f);
                if (node < n)
                    v = *reinterpret_cast<const float4*>(&x[(size_t)node * FIN + kc + k4 * 4]);
                ra[i] = v;
            }
#pragma unroll
            for (int i = 0; i < 2; ++i)
                rb[i] = *reinterpret_cast<const uint4*>(
                    &Wt[(size_t)(nr0 + i * 32) * FIN + kc + seg * 8]);
        }

#pragma unroll
        for (int kk = 0; kk < 2; ++kk) {
            short8 a[2], b[4];
#pragma unroll
            for (int mt = 0; mt < 2; ++mt)
                a[mt] = *reinterpret_cast<const short8*>(
                    &lA[(wave * 32 + mt * 16 + m16) * LDA + kk * 32 + quad * 8]);
#pragma unroll
            for (int nt = 0; nt < 4; ++nt)
                b[nt] = *reinterpret_cast<const short8*>(
                    &lB[(nt * 16 + m16) * LDB + kk * 32 + quad * 8]);
#pragma unroll
            for (int mt = 0; mt < 2; ++mt)
#pragma unroll
                for (int nt = 0; nt < 4; ++nt)
                    acc[mt][nt] = __builtin_amdgcn_mfma_f32_16x16x32_bf16(
                        a[mt], b[nt], acc[mt][nt], 0, 0, 0);
        }
        __syncthreads();
    }

#pragma unroll
    for (int mt = 0; mt < 2; ++mt) {
#pragma unroll
        for (int reg = 0; reg < 4; ++reg) {
            int node = node0 + wave * 32 + mt * 16 + quad * 4 + reg;
            if (node < n) {
#pragma unroll
                for (int nt = 0; nt < 4; ++nt)
                    h1b[(size_t)node * 64 + nt * 16 + m16] = bf16_rn(acc[mt][nt][reg]);
            }
        }
    }
}

// ---------------- pure aggregation kernel (templated) ----------------
// wave = node; 8 edge-groups x 8 feat-chunks x 16B gathers, chunk-32 (4 in
// flight); nm = dinv[src] gathered from L2-resident table; cross-edge reduce
// via one LDS transpose (stride-68 pad: balanced write banks, conflict-free
// reads). MODE 0: dst = bf16(relu(agg + b1));  MODE 1: dst = bf16(agg).
template <int MODE>
__global__ __launch_bounds__(256) void agg_kernel(
    const int* __restrict__ offs, const int* __restrict__ deg,
    const int* __restrict__ sSrc, const ushort_t* __restrict__ src,
    const float* __restrict__ dinv, const float* __restrict__ b1,
    ushort_t* __restrict__ dst, int n) {
    __shared__ float lacc[4][8 * 68];   // 8704 B: [wave][e8-group*68 + feat]
    __shared__ float lb1[64];
    int tid = threadIdx.x;
    if (MODE == 0 && tid < 64) lb1[tid] = b1[tid];

    int wv = tid >> 6, lane = tid & 63;
    int e8 = lane >> 3, c = lane & 7;
    int node = blockIdx.x * 4 + wv;
    bool valid = node < n;
    int start = valid ? offs[node] : 0;
    int cnt = valid ? deg[node] : 0;

    float acc[8];
#pragma unroll
    for (int j = 0; j < 8; ++j) acc[j] = 0.f;

    for (int base = 0; base < cnt; base += 32) {
        int i0 = base + e8, i1 = i0 + 8, i2 = i0 + 16, i3 = i0 + 24;
        int s0 = (i0 < cnt) ? sSrc[start + i0] : 0;
        int s1 = (i1 < cnt) ? sSrc[start + i1] : 0;
        int s2 = (i2 < cnt) ? sSrc[start + i2] : 0;
        int s3 = (i3 < cnt) ? sSrc[start + i3] : 0;
        float nm0 = (i0 < cnt) ? dinv[s0] : 0.f;   // mask: padded slots add 0
        float nm1 = (i1 < cnt) ? dinv[s1] : 0.f;
        float nm2 = (i2 < cnt) ? dinv[s2] : 0.f;
        float nm3 = (i3 < cnt) ? dinv[s3] : 0.f;
        uint4 g0 = *reinterpret_cast<const uint4*>(&src[(size_t)s0 * 64 + c * 8]);
        uint4 g1 = *reinterpret_cast<const uint4*>(&src[(size_t)s1 * 64 + c * 8]);
        uint4 g2 = *reinterpret_cast<const uint4*>(&src[(size_t)s2 * 64 + c * 8]);
        uint4 g3 = *reinterpret_cast<const uint4*>(&src[(size_t)s3 * 64 + c * 8]);
        acc8(acc, g0, nm0);
        acc8(acc, g1, nm1);
        acc8(acc, g2, nm2);
        acc8(acc, g3, nm3);
    }

    // LDS transpose-reduce: lane (e8,c) -> lacc[wv][e8*68 + c*8 ..], then
    // lane f sums the 8 e8-groups at feat f.
    {
        float* lw = &lacc[wv][e8 * 68 + c * 8];
        *reinterpret_cast<float4*>(lw) = make_float4(acc[0], acc[1], acc[2], acc[3]);
        *reinterpret_cast<float4*>(lw + 4) = make_float4(acc[4], acc[5], acc[6], acc[7]);
    }
    __syncthreads();

    if (valid) {
        float s = 0.f;
#pragma unroll
        for (int g = 0; g < 8; ++g) s += lacc[wv][g * 68 + lane];
        float di = dinv[node];
        float self = bf16_to_f(src[(size_t)node * 64 + lane]) * di;
        float v = (s + self) * di;
        if (MODE == 0) v = fmaxf(v + lb1[lane], 0.f);
        dst[(size_t)node * 64 + lane] = bf16_rn(v);
    }
}

// ---------------- GEMM2 + bias + log_softmax (MFMA) ----------------
// out[N,40] = log_softmax( A[N,64] @ W2[64,40] + b2 ), W2 as hi+lo bf16.
// Tile: 128 nodes x 48 cols, K=64 (single stage). C-layout epilogue softmax.
#define LDC 72
__global__ __launch_bounds__(256) void gemm2sm_kernel(
    const ushort_t* __restrict__ A, const ushort_t* __restrict__ w2hi,
    const ushort_t* __restrict__ w2lo, const float* __restrict__ b2,
    float* __restrict__ out, int n) {
    __shared__ ushort_t lA[128 * LDC];
    __shared__ ushort_t lBh[48 * LDC];
    __shared__ ushort_t lBl[48 * LDC];

    int tid = threadIdx.x;
    int wave = tid >> 6, lane = tid & 63;
    int quad = lane >> 4, m16 = lane & 15;
    int node0 = blockIdx.x * 128;

    // stage A tile: 128 rows x 64 bf16; 2 threads/row, 64B each
    {
        int r = tid & 127, part = tid >> 7;
        int node = node0 + r;
        uint4 z = make_uint4(0u, 0u, 0u, 0u);
        const uint4* sp = reinterpret_cast<const uint4*>(&A[(size_t)node * 64 + part * 32]);
#pragma unroll
        for (int i = 0; i < 4; ++i) {
            uint4 v = (node < n) ? sp[i] : z;
            *reinterpret_cast<uint4*>(&lA[r * LDC + part * 32 + i * 8]) = v;
        }
    }
    // stage B tiles: 48*64 bf16 = 384 uint4 each
    for (int i = tid; i < 384; i += 256) {
        int row = i >> 3, seg = i & 7;
        *reinterpret_cast<uint4*>(&lBh[row * LDC + seg * 8]) =
            reinterpret_cast<const uint4*>(w2hi)[i];
        *reinterpret_cast<uint4*>(&lBl[row * LDC + seg * 8]) =
            reinterpret_cast<const uint4*>(w2lo)[i];
    }
    // per-lane bias (j = nt*16 + m16)
    float rb2_0 = b2[m16];
    float rb2_1 = b2[16 + m16];
    float rb2_2 = (m16 < 8) ? b2[32 + m16] : 0.f;
    __syncthreads();

    f32x4 zero = {0.f, 0.f, 0.f, 0.f};
    f32x4 acc[2][3];
#pragma unroll
    for (int mt = 0; mt < 2; ++mt)
#pragma unroll
        for (int nt = 0; nt < 3; ++nt) acc[mt][nt] = zero;

#pragma unroll
    for (int kk = 0; kk < 2; ++kk) {
        short8 a[2], bh[3], bl[3];
#pragma unroll
        for (int mt = 0; mt < 2; ++mt)
            a[mt] = *reinterpret_cast<const short8*>(
                &lA[(wave * 32 + mt * 16 + m16) * LDC + kk * 32 + quad * 8]);
#pragma unroll
        for (int nt = 0; nt < 3; ++nt) {
            bh[nt] = *reinterpret_cast<const short8*>(
                &lBh[(nt * 16 + m16) * LDC + kk * 32 + quad * 8]);
            bl[nt] = *reinterpret_cast<const short8*>(
                &lBl[(nt * 16 + m16) * LDC + kk * 32 + quad * 8]);
        }
#pragma unroll
        for (int mt = 0; mt < 2; ++mt)
#pragma unroll
            for (int nt = 0; nt < 3; ++nt) {
                acc[mt][nt] = __builtin_amdgcn_mfma_f32_16x16x32_bf16(
                    a[mt], bh[nt], acc[mt][nt], 0, 0, 0);
                acc[mt][nt] = __builtin_amdgcn_mfma_f32_16x16x32_bf16(
                    a[mt], bl[nt], acc[mt][nt], 0, 0, 0);
            }
    }

    // epilogue: bias + log_softmax per node-row (cols spread over 16 lanes x 3 nt)
    bool c2 = (m16 < 8);   // nt=2 col j=32+m16 valid iff m16<8
#pragma unroll
    for (int mt = 0; mt < 2; ++mt) {
#pragma unroll
        for (int reg = 0; reg < 4; ++reg) {
            int node = node0 + wave * 32 + mt * 16 + quad * 4 + reg;
            float r0 = acc[mt][0][reg] + rb2_0;
            float r1 = acc[mt][1][reg] + rb2_1;
            float r2 = acc[mt][2][reg] + rb2_2;
            float pm = fmaxf(fmaxf(r0, r1), c2 ? r2 : -INFINITY);
#pragma unroll
            for (int mask = 1; mask <= 8; mask <<= 1)
                pm = fmaxf(pm, __shfl_xor(pm, mask));
            float s = expf(r0 - pm) + expf(r1 - pm) + (c2 ? expf(r2 - pm) : 0.f);
#pragma unroll
            for (int mask = 1; mask <= 8; mask <<= 1)
                s += __shfl_xor(s, mask);
            float ls = logf(s) + pm;
            if (node < n) {
                float* op = &out[(size_t)node * FOUT];
                op[m16] = r0 - ls;
                op[16 + m16] = r1 - ls;
                if (c2) op[32 + m16] = r2 - ls;
            }
        }
    }
}

// ---------------------------------------------------------------------------
extern "C" void kernel_launch(void* const* d_in, const int* in_sizes, int n_in,
                              void* d_out, int out_size, void* d_ws, size_t ws_size,
                              hipStream_t stream) {
    const float* x  = (const float*)d_in[0];
    const int*   ei = (const int*)d_in[1];
    const float* W1 = (const float*)d_in[2];
    const float* b1 = (const float*)d_in[3];
    const float* W2 = (const float*)d_in[4];
    const float* b2 = (const float*)d_in[5];
    float* out = (float*)d_out;

    int n = in_sizes[0] / FIN;        // 100000
    int E = in_sizes[1] / 2;          // 1600000
    const int* row = ei;
    const int* col = ei + E;

    // workspace layout (4-byte words), ~34 MB total
    int* wsi = (int*)d_ws;
    const size_t NR = 100352;
    int*      deg    = wsi;                                  // [NR]
    float*    dinv   = (float*)(wsi + NR);                   // [NR]
    int*      offs   = wsi + 2 * NR;                         // [NR]
    int*      cursor = wsi + 3 * NR;                         // [NR]
    int*      bsums  = wsi + 4 * NR;                         // [512]
    ushort_t* Wt     = (ushort_t*)(wsi + 4 * NR + 512);      // [64*512] bf16
    ushort_t* w2hi   = Wt + 64 * 512;                        // [48*64] bf16
    ushort_t* w2lo   = w2hi + 48 * 64;                       // [48*64] bf16
    int*      sSrc   = (int*)(w2lo + 48 * 64);               // [E] src index
    ushort_t* h1b    = (ushort_t*)(sSrc + (size_t)E);        // [n*64] bf16 (then A)
    ushort_t* h1a    = h1b + (size_t)n * 64;                 // [n*64] bf16
    ushort_t* Abuf   = h1b;                                  // reuse: h1b dead after agg<0>

    int nb = (n + 255) / 256;   // 391

    // ---- CSR build ----
    hipMemsetAsync(deg, 0, (size_t)n * 4, stream);
    hist_kernel<<<(E / 4 + 255) / 256, 256, 0, stream>>>(col, deg, E);
    scan1_kernel<<<nb, 256, 0, stream>>>(deg, offs, bsums, dinv, n);
    scan2_kernel<<<1, 512, 0, stream>>>(bsums, nb);
    scan3_kernel<<<nb, 256, 0, stream>>>(offs, bsums, cursor, n);
    build_kernel<<<(E + 255) / 256, 256, 0, stream>>>(row, col, cursor, sSrc, E);

    // ---- weights prep (W1^T + W2 hi/lo split, one kernel) ----
    wprep_kernel<<<140, 256, 0, stream>>>(W1, W2, Wt, w2hi, w2lo);

    // ---- layer 1 transform ----
    gemm1_kernel<<<(n + 127) / 128, 256, 0, stream>>>(x, Wt, h1b, n);

    // ---- aggregation 1 (+bias+relu) -> h1a ----
    agg_kernel<0><<<(n + 3) / 4, 256, 0, stream>>>(offs, deg, sSrc, h1b, dinv, b1, h1a, n);

    // ---- aggregation 2 (pure) -> Abuf ----
    agg_kernel<1><<<(n + 3) / 4, 256, 0, stream>>>(offs, deg, sSrc, h1a, dinv, b1, Abuf, n);

    // ---- layer 2 transform + bias + log_softmax ----
    gemm2sm_kernel<<<(n + 127) / 128, 256, 0, stream>>>(Abuf, w2hi, w2lo, b2, out, n);
}

// Round 5
// 461.722 us; speedup vs baseline: 1.3112x; 1.3112x over previous
//
#include <hip/hip_runtime.h>
#include <math.h>

// ---------------------------------------------------------------------------
// GCN 2-layer: h1 = relu(gcnconv(x,W1,b1)); out = log_softmax(gcnconv(h1,W2,b2))
// R11: CSR build rebuilt as a two-level counting sort (the R10 profile showed
// build_kernel at 133-138us with 106MB WRITE_SIZE from random 4B scatters +
// cross-XCD false sharing + 1.6M atomics-with-return):
//  - B1 bucket_scatter: 256-node buckets; per-WG LDS histogram + one global
//    atomic claim per (WG,bucket); packed (row<<8|col&255) staged contiguous.
//  - B2 bucket_place: one WG per bucket; LDS hist + LDS scan -> writes
//    deg/dinv/offs for its nodes AND final sSrc via LDS cursors (scatter
//    confined to a 16KB single-WG window -> dense writebacks, 0 global atomics).
//  - hist_kernel / scan1 / scan3 deleted (deg,offs,dinv now fall out of B2;
//    scan2 reused verbatim to scan the 391 bucket totals).
// Structure from R9/R10: out = log_softmax( agg2(relu(agg1(x@W1)+b1)) @ W2+b2 )
// gemm1/gemm2sm via bf16 MFMA; agg = pure gather+reduce, LDS transpose-reduce.
// N=100000, E=1600000, F: 512 -> 64 -> 40
// ---------------------------------------------------------------------------

#define FIN 512
#define FHID 64
#define FOUT 40

#define BSH 8          // log2(nodes per bucket)
#define BN 256         // nodes per bucket
#define BCAP 5120      // staging capacity per bucket (mean 4096, +16 sigma)
#define EPW 4096       // edges per workgroup in B1

typedef __attribute__((ext_vector_type(8))) short short8;
typedef __attribute__((ext_vector_type(4))) float f32x4;
typedef unsigned short ushort_t;
typedef unsigned int uint_t;

__device__ __forceinline__ ushort_t bf16_rn(float f) {
    union { float f; uint_t u; } v; v.f = f;
    uint_t r = v.u + 0x7FFF + ((v.u >> 16) & 1);
    return (ushort_t)(r >> 16);
}
__device__ __forceinline__ uint_t pack_bf16(float a, float b) {
    return (uint_t)bf16_rn(a) | ((uint_t)bf16_rn(b) << 16);
}
__device__ __forceinline__ float bf16_to_f(ushort_t u) {
    union { uint_t i; float f; } t; t.i = ((uint_t)u) << 16; return t.f;
}
// accumulate 8 bf16 feats (one uint4) * nm into acc[8]
__device__ __forceinline__ void acc8(float* acc, uint4 g, float nm) {
    acc[0] = fmaf(__uint_as_float(g.x << 16), nm, acc[0]);
    acc[1] = fmaf(__uint_as_float(g.x & 0xFFFF0000u), nm, acc[1]);
    acc[2] = fmaf(__uint_as_float(g.y << 16), nm, acc[2]);
    acc[3] = fmaf(__uint_as_float(g.y & 0xFFFF0000u), nm, acc[3]);
    acc[4] = fmaf(__uint_as_float(g.z << 16), nm, acc[4]);
    acc[5] = fmaf(__uint_as_float(g.z & 0xFFFF0000u), nm, acc[5]);
    acc[6] = fmaf(__uint_as_float(g.w << 16), nm, acc[6]);
    acc[7] = fmaf(__uint_as_float(g.w & 0xFFFF0000u), nm, acc[7]);
}

// ---------------- B1: bucket scatter ----------------
// Each WG handles EPW edges: LDS histogram over buckets, one global atomic
// claim per (WG,bucket), LDS-atomic ranks, contiguous staged writes.
__global__ __launch_bounds__(256) void bucket_scatter_kernel(
    const int* __restrict__ row, const int* __restrict__ col,
    int* __restrict__ gcur, uint_t* __restrict__ stage, int E) {
    __shared__ uint_t cnt[512];
    __shared__ uint_t base[512];
    int tid = threadIdx.x;
    cnt[tid] = 0; cnt[tid + 256] = 0;
    __syncthreads();
    int e0 = blockIdx.x * EPW;
    int creg[16];
#pragma unroll
    for (int it = 0; it < 16; ++it) {
        int e = e0 + it * 256 + tid;
        creg[it] = (e < E) ? col[e] : -1;
        if (e < E) atomicAdd(&cnt[((uint_t)creg[it]) >> BSH], 1u);
    }
    __syncthreads();
    uint_t c0 = cnt[tid], c1 = cnt[tid + 256];
    base[tid] = c0 ? (uint_t)atomicAdd(&gcur[tid], (int)c0) : 0u;
    base[tid + 256] = c1 ? (uint_t)atomicAdd(&gcur[tid + 256], (int)c1) : 0u;
    __syncthreads();
    cnt[tid] = 0; cnt[tid + 256] = 0;
    __syncthreads();
#pragma unroll
    for (int it = 0; it < 16; ++it) {
        int e = e0 + it * 256 + tid;
        if (e < E) {
            int c = creg[it];
            int r = row[e];
            int b = c >> BSH;
            uint_t slot = base[b] + atomicAdd(&cnt[b], 1u);
            stage[(size_t)b * BCAP + slot] = ((uint_t)r << BSH) | (uint_t)(c & (BN - 1));
        }
    }
}

// ---------------- scan (in-place exclusive, <=512 entries) ----------------
__global__ void scan2_kernel(int* __restrict__ bsums, int nb) {
    __shared__ int tmp[512];
    int tid = threadIdx.x;
    int v = (tid < nb) ? bsums[tid] : 0;
    tmp[tid] = v;
    __syncthreads();
    for (int off = 1; off < 512; off <<= 1) {
        int t = (tid >= off) ? tmp[tid - off] : 0;
        __syncthreads();
        tmp[tid] += t;
        __syncthreads();
    }
    if (tid < nb) bsums[tid] = tmp[tid] - v;
}

// ---------------- B2: per-bucket final placement + deg/dinv/offs ----------
__global__ __launch_bounds__(256) void bucket_place_kernel(
    const int* __restrict__ gcur, const uint_t* __restrict__ stage,
    int* __restrict__ sSrc, int* __restrict__ deg, float* __restrict__ dinv,
    int* __restrict__ offs, int n) {
    __shared__ int lcnt[256];
    __shared__ int ltmp[256];
    __shared__ int lpos[256];
    int b = blockIdx.x, tid = threadIdx.x;
    int nodeBase = b << BSH;
    int bucketBase = gcur[b];
    int cnt = gcur[b + 1] - bucketBase;
    lcnt[tid] = 0;
    __syncthreads();
    const uint_t* sp = &stage[(size_t)b * BCAP];
    for (int i = tid; i < cnt; i += 256)
        atomicAdd(&lcnt[sp[i] & (BN - 1)], 1);
    __syncthreads();
    int v = lcnt[tid];
    ltmp[tid] = v;
    __syncthreads();
    for (int off = 1; off < 256; off <<= 1) {
        int t = (tid >= off) ? ltmp[tid - off] : 0;
        __syncthreads();
        ltmp[tid] += t;
        __syncthreads();
    }
    int gofs = bucketBase + ltmp[tid] - v;   // global exclusive offset for node
    int node = nodeBase + tid;
    if (node < n) {
        deg[node] = v;
        dinv[node] = rsqrtf((float)v + 1.0f);
        offs[node] = gofs;
    }
    lpos[tid] = gofs;
    __syncthreads();
    for (int i = tid; i < cnt; i += 256) {
        uint_t w = sp[i];
        int pos = atomicAdd(&lpos[w & (BN - 1)], 1);
        sSrc[pos] = (int)(w >> BSH);
    }
}

// ---------------- weights prep: W1^T bf16 + W2^T hi/lo bf16 split ----------
// Wt: [64][512] bf16. w2hi/w2lo: [48][64] bf16, rows 40..47 zero.
__global__ void wprep_kernel(const float* __restrict__ W1, const float* __restrict__ W2,
                             ushort_t* __restrict__ Wt,
                             ushort_t* __restrict__ w2hi, ushort_t* __restrict__ w2lo) {
    int idx = blockIdx.x * 256 + threadIdx.x;   // 35840 = 32768 + 3072
    if (idx < 32768) {
        int nrow = idx >> 9;
        int k = idx & 511;
        Wt[idx] = bf16_rn(W1[k * 64 + nrow]);
    } else if (idx < 32768 + 3072) {
        int i = idx - 32768;
        int j = i >> 6, k = i & 63;
        float w = (j < FOUT) ? W2[k * FOUT + j] : 0.f;
        ushort_t h = bf16_rn(w);
        w2hi[i] = h;
        w2lo[i] = bf16_rn(w - bf16_to_f(h));
    }
}

// ---------------- GEMM1 (MFMA): h1b[N,64] = bf16( x[N,512] @ W1[512,64] ) ----
// register-prefetch pipeline (single LDS buffer).
#define LDA 72
#define LDB 72
__global__ __launch_bounds__(256) void gemm1_kernel(
    const float* __restrict__ x, const ushort_t* __restrict__ Wt,
    ushort_t* __restrict__ h1b, int n) {
    __shared__ ushort_t lA[128 * LDA];
    __shared__ ushort_t lB[64 * LDB];

    int tid = threadIdx.x;
    int wave = tid >> 6, lane = tid & 63;
    int quad = lane >> 4, m16 = lane & 15;
    int node0 = blockIdx.x * 128;

    int r0 = tid >> 4, k4 = tid & 15;    // A: rows r0+16i, 16B at col k4*4
    int nr0 = tid >> 3, seg = tid & 7;   // B: rows nr0+32i, 16B at col seg*8

    f32x4 zero = {0.f, 0.f, 0.f, 0.f};
    f32x4 acc[2][4];
#pragma unroll
    for (int mt = 0; mt < 2; ++mt)
#pragma unroll
        for (int nt = 0; nt < 4; ++nt) acc[mt][nt] = zero;

    float4 ra[8];
    uint4 rb[2];

#pragma unroll
    for (int i = 0; i < 8; ++i) {
        int node = node0 + r0 + i * 16;
        float4 v = make_float4(0.f, 0.f, 0.f, 0.f);
        if (node < n) v = *reinterpret_cast<const float4*>(&x[(size_t)node * FIN + k4 * 4]);
        ra[i] = v;
    }
#pragma unroll
    for (int i = 0; i < 2; ++i)
        rb[i] = *reinterpret_cast<const uint4*>(&Wt[(size_t)(nr0 + i * 32) * FIN + seg * 8]);

    for (int c = 0; c < 8; ++c) {
#pragma unroll
        for (int i = 0; i < 8; ++i)
            *reinterpret_cast<uint2*>(&lA[(r0 + i * 16) * LDA + k4 * 4]) =
                make_uint2(pack_bf16(ra[i].x, ra[i].y), pack_bf16(ra[i].z, ra[i].w));
#pragma unroll
        for (int i = 0; i < 2; ++i)
            *reinterpret_cast<uint4*>(&lB[(nr0 + i * 32) * LDB + seg * 8]) = rb[i];
        __syncthreads();

        if (c < 7) {
            int kc = (c + 1) * 64;
#pragma unroll
            for (int i = 0; i < 8; ++i) {
                int node = node0 + r0 + i * 16;
                float4 v = make_float4(0.f, 0.f, 0.f, 0.f);
                if (node < n)
                    v = *reinterpret_cast<const float4*>(&x[(size_t)node * FIN + kc + k4 * 4]);
                ra[i] = v;
            }
#pragma unroll
            for (int i = 0; i < 2; ++i)
                rb[i] = *reinterpret_cast<const uint4*>(
                    &Wt[(size_t)(nr0 + i * 32) * FIN + kc + seg * 8]);
        }

#pragma unroll
        for (int kk = 0; kk < 2; ++kk) {
            short8 a[2], b[4];
#pragma unroll
            for (int mt = 0; mt < 2; ++mt)
                a[mt] = *reinterpret_cast<const short8*>(
                    &lA[(wave * 32 + mt * 16 + m16) * LDA + kk * 32 + quad * 8]);
#pragma unroll
            for (int nt = 0; nt < 4; ++nt)
                b[nt] = *reinterpret_cast<const short8*>(
                    &lB[(nt * 16 + m16) * LDB + kk * 32 + quad * 8]);
#pragma unroll
            for (int mt = 0; mt < 2; ++mt)
#pragma unroll
                for (int nt = 0; nt < 4; ++nt)
                    acc[mt][nt] = __builtin_amdgcn_mfma_f32_16x16x32_bf16(
                        a[mt], b[nt], acc[mt][nt], 0, 0, 0);
        }
        __syncthreads();
    }

#pragma unroll
    for (int mt = 0; mt < 2; ++mt) {
#pragma unroll
        for (int reg = 0; reg < 4; ++reg) {
            int node = node0 + wave * 32 + mt * 16 + quad * 4 + reg;
            if (node < n) {
#pragma unroll
                for (int nt = 0; nt < 4; ++nt)
                    h1b[(size_t)node * 64 + nt * 16 + m16] = bf16_rn(acc[mt][nt][reg]);
            }
        }
    }
}

// ---------------- pure aggregation kernel (templated) ----------------
// wave = node; 8 edge-groups x 8 feat-chunks x 16B gathers, chunk-32 (4 in
// flight); nm = dinv[src] gathered from L2-resident table; cross-edge reduce
// via one LDS transpose (stride-68 pad: balanced banks, conflict-free reads).
// MODE 0: dst = bf16(relu(agg + b1));  MODE 1: dst = bf16(agg).
template <int MODE>
__global__ __launch_bounds__(256) void agg_kernel(
    const int* __restrict__ offs, const int* __restrict__ deg,
    const int* __restrict__ sSrc, const ushort_t* __restrict__ src,
    const float* __restrict__ dinv, const float* __restrict__ b1,
    ushort_t* __restrict__ dst, int n) {
    __shared__ float lacc[4][8 * 68];   // 8704 B: [wave][e8-group*68 + feat]
    __shared__ float lb1[64];
    int tid = threadIdx.x;
    if (MODE == 0 && tid < 64) lb1[tid] = b1[tid];

    int wv = tid >> 6, lane = tid & 63;
    int e8 = lane >> 3, c = lane & 7;
    int node = blockIdx.x * 4 + wv;
    bool valid = node < n;
    int start = valid ? offs[node] : 0;
    int cnt = valid ? deg[node] : 0;

    float acc[8];
#pragma unroll
    for (int j = 0; j < 8; ++j) acc[j] = 0.f;

    for (int base = 0; base < cnt; base += 32) {
        int i0 = base + e8, i1 = i0 + 8, i2 = i0 + 16, i3 = i0 + 24;
        int s0 = (i0 < cnt) ? sSrc[start + i0] : 0;
        int s1 = (i1 < cnt) ? sSrc[start + i1] : 0;
        int s2 = (i2 < cnt) ? sSrc[start + i2] : 0;
        int s3 = (i3 < cnt) ? sSrc[start + i3] : 0;
        float nm0 = (i0 < cnt) ? dinv[s0] : 0.f;   // mask: padded slots add 0
        float nm1 = (i1 < cnt) ? dinv[s1] : 0.f;
        float nm2 = (i2 < cnt) ? dinv[s2] : 0.f;
        float nm3 = (i3 < cnt) ? dinv[s3] : 0.f;
        uint4 g0 = *reinterpret_cast<const uint4*>(&src[(size_t)s0 * 64 + c * 8]);
        uint4 g1 = *reinterpret_cast<const uint4*>(&src[(size_t)s1 * 64 + c * 8]);
        uint4 g2 = *reinterpret_cast<const uint4*>(&src[(size_t)s2 * 64 + c * 8]);
        uint4 g3 = *reinterpret_cast<const uint4*>(&src[(size_t)s3 * 64 + c * 8]);
        acc8(acc, g0, nm0);
        acc8(acc, g1, nm1);
        acc8(acc, g2, nm2);
        acc8(acc, g3, nm3);
    }

    // LDS transpose-reduce: lane (e8,c) -> lacc[wv][e8*68 + c*8 ..], then
    // lane f sums the 8 e8-groups at feat f.
    {
        float* lw = &lacc[wv][e8 * 68 + c * 8];
        *reinterpret_cast<float4*>(lw) = make_float4(acc[0], acc[1], acc[2], acc[3]);
        *reinterpret_cast<float4*>(lw + 4) = make_float4(acc[4], acc[5], acc[6], acc[7]);
    }
    __syncthreads();

    if (valid) {
        float s = 0.f;
#pragma unroll
        for (int g = 0; g < 8; ++g) s += lacc[wv][g * 68 + lane];
        float di = dinv[node];
        float self = bf16_to_f(src[(size_t)node * 64 + lane]) * di;
        float v = (s + self) * di;
        if (MODE == 0) v = fmaxf(v + lb1[lane], 0.f);
        dst[(size_t)node * 64 + lane] = bf16_rn(v);
    }
}

// ---------------- GEMM2 + bias + log_softmax (MFMA) ----------------
// out[N,40] = log_softmax( A[N,64] @ W2[64,40] + b2 ), W2 as hi+lo bf16.
// Tile: 128 nodes x 48 cols, K=64 (single stage). C-layout epilogue softmax.
#define LDC 72
__global__ __launch_bounds__(256) void gemm2sm_kernel(
    const ushort_t* __restrict__ A, const ushort_t* __restrict__ w2hi,
    const ushort_t* __restrict__ w2lo, const float* __restrict__ b2,
    float* __restrict__ out, int n) {
    __shared__ ushort_t lA[128 * LDC];
    __shared__ ushort_t lBh[48 * LDC];
    __shared__ ushort_t lBl[48 * LDC];

    int tid = threadIdx.x;
    int wave = tid >> 6, lane = tid & 63;
    int quad = lane >> 4, m16 = lane & 15;
    int node0 = blockIdx.x * 128;

    // stage A tile: 128 rows x 64 bf16; 2 threads/row, 64B each
    {
        int r = tid & 127, part = tid >> 7;
        int node = node0 + r;
        uint4 z = make_uint4(0u, 0u, 0u, 0u);
        const uint4* sp = reinterpret_cast<const uint4*>(&A[(size_t)node * 64 + part * 32]);
#pragma unroll
        for (int i = 0; i < 4; ++i) {
            uint4 v = (node < n) ? sp[i] : z;
            *reinterpret_cast<uint4*>(&lA[r * LDC + part * 32 + i * 8]) = v;
        }
    }
    // stage B tiles: 48*64 bf16 = 384 uint4 each
    for (int i = tid; i < 384; i += 256) {
        int row = i >> 3, seg = i & 7;
        *reinterpret_cast<uint4*>(&lBh[row * LDC + seg * 8]) =
            reinterpret_cast<const uint4*>(w2hi)[i];
        *reinterpret_cast<uint4*>(&lBl[row * LDC + seg * 8]) =
            reinterpret_cast<const uint4*>(w2lo)[i];
    }
    // per-lane bias (j = nt*16 + m16)
    float rb2_0 = b2[m16];
    float rb2_1 = b2[16 + m16];
    float rb2_2 = (m16 < 8) ? b2[32 + m16] : 0.f;
    __syncthreads();

    f32x4 zero = {0.f, 0.f, 0.f, 0.f};
    f32x4 acc[2][3];
#pragma unroll
    for (int mt = 0; mt < 2; ++mt)
#pragma unroll
        for (int nt = 0; nt < 3; ++nt) acc[mt][nt] = zero;

#pragma unroll
    for (int kk = 0; kk < 2; ++kk) {
        short8 a[2], bh[3], bl[3];
#pragma unroll
        for (int mt = 0; mt < 2; ++mt)
            a[mt] = *reinterpret_cast<const short8*>(
                &lA[(wave * 32 + mt * 16 + m16) * LDC + kk * 32 + quad * 8]);
#pragma unroll
        for (int nt = 0; nt < 3; ++nt) {
            bh[nt] = *reinterpret_cast<const short8*>(
                &lBh[(nt * 16 + m16) * LDC + kk * 32 + quad * 8]);
            bl[nt] = *reinterpret_cast<const short8*>(
                &lBl[(nt * 16 + m16) * LDC + kk * 32 + quad * 8]);
        }
#pragma unroll
        for (int mt = 0; mt < 2; ++mt)
#pragma unroll
            for (int nt = 0; nt < 3; ++nt) {
                acc[mt][nt] = __builtin_amdgcn_mfma_f32_16x16x32_bf16(
                    a[mt], bh[nt], acc[mt][nt], 0, 0, 0);
                acc[mt][nt] = __builtin_amdgcn_mfma_f32_16x16x32_bf16(
                    a[mt], bl[nt], acc[mt][nt], 0, 0, 0);
            }
    }

    // epilogue: bias + log_softmax per node-row (cols spread over 16 lanes x 3 nt)
    bool c2 = (m16 < 8);   // nt=2 col j=32+m16 valid iff m16<8
#pragma unroll
    for (int mt = 0; mt < 2; ++mt) {
#pragma unroll
        for (int reg = 0; reg < 4; ++reg) {
            int node = node0 + wave * 32 + mt * 16 + quad * 4 + reg;
            float r0 = acc[mt][0][reg] + rb2_0;
            float r1 = acc[mt][1][reg] + rb2_1;
            float r2 = acc[mt][2][reg] + rb2_2;
            float pm = fmaxf(fmaxf(r0, r1), c2 ? r2 : -INFINITY);
#pragma unroll
            for (int mask = 1; mask <= 8; mask <<= 1)
                pm = fmaxf(pm, __shfl_xor(pm, mask));
            float s = expf(r0 - pm) + expf(r1 - pm) + (c2 ? expf(r2 - pm) : 0.f);
#pragma unroll
            for (int mask = 1; mask <= 8; mask <<= 1)
                s += __shfl_xor(s, mask);
            float ls = logf(s) + pm;
            if (node < n) {
                float* op = &out[(size_t)node * FOUT];
                op[m16] = r0 - ls;
                op[16 + m16] = r1 - ls;
                if (c2) op[32 + m16] = r2 - ls;
            }
        }
    }
}

// ---------------------------------------------------------------------------
extern "C" void kernel_launch(void* const* d_in, const int* in_sizes, int n_in,
                              void* d_out, int out_size, void* d_ws, size_t ws_size,
                              hipStream_t stream) {
    const float* x  = (const float*)d_in[0];
    const int*   ei = (const int*)d_in[1];
    const float* W1 = (const float*)d_in[2];
    const float* b1 = (const float*)d_in[3];
    const float* W2 = (const float*)d_in[4];
    const float* b2 = (const float*)d_in[5];
    float* out = (float*)d_out;

    int n = in_sizes[0] / FIN;        // 100000
    int E = in_sizes[1] / 2;          // 1600000
    const int* row = ei;
    const int* col = ei + E;

    // workspace layout (4-byte words), ~44 MB total
    int* wsi = (int*)d_ws;
    const size_t NR = 100352;
    int*      deg   = wsi;                                  // [NR]
    float*    dinv  = (float*)(wsi + NR);                   // [NR]
    int*      offs  = wsi + 2 * NR;                         // [NR]
    int*      gcur  = wsi + 3 * NR;                         // [512] bucket cnt/base
    ushort_t* Wt    = (ushort_t*)(wsi + 3 * NR + 512);      // [64*512] bf16
    ushort_t* w2hi  = Wt + 64 * 512;                        // [48*64] bf16
    ushort_t* w2lo  = w2hi + 48 * 64;                       // [48*64] bf16
    uint_t*   stage = (uint_t*)(w2lo + 48 * 64);            // [512*BCAP]
    int*      sSrc  = (int*)(stage + (size_t)512 * BCAP);   // [E]
    ushort_t* h1b   = (ushort_t*)(sSrc + (size_t)E);        // [n*64] bf16 (then A)
    ushort_t* h1a   = h1b + (size_t)n * 64;                 // [n*64] bf16
    ushort_t* Abuf  = h1b;                                  // reuse after agg<0>

    int NBUCK = (n + BN - 1) >> BSH;       // 391
    int nwg1 = (E + EPW - 1) / EPW;        // 391

    // ---- CSR build (two-level counting sort) ----
    hipMemsetAsync(gcur, 0, 512 * 4, stream);
    bucket_scatter_kernel<<<nwg1, 256, 0, stream>>>(row, col, gcur, stage, E);
    scan2_kernel<<<1, 512, 0, stream>>>(gcur, 512);
    bucket_place_kernel<<<NBUCK, 256, 0, stream>>>(gcur, stage, sSrc, deg, dinv, offs, n);

    // ---- weights prep (W1^T + W2 hi/lo split, one kernel) ----
    wprep_kernel<<<140, 256, 0, stream>>>(W1, W2, Wt, w2hi, w2lo);

    // ---- layer 1 transform ----
    gemm1_kernel<<<(n + 127) / 128, 256, 0, stream>>>(x, Wt, h1b, n);

    // ---- aggregation 1 (+bias+relu) -> h1a ----
    agg_kernel<0><<<(n + 3) / 4, 256, 0, stream>>>(offs, deg, sSrc, h1b, dinv, b1, h1a, n);

    // ---- aggregation 2 (pure) -> Abuf ----
    agg_kernel<1><<<(n + 3) / 4, 256, 0, stream>>>(offs, deg, sSrc, h1a, dinv, b1, Abuf, n);

    // ---- layer 2 transform + bias + log_softmax ----
    gemm2sm_kernel<<<(n + 127) / 128, 256, 0, stream>>>(Abuf, w2hi, w2lo, b2, out, n);
}

// Round 7
// 445.889 us; speedup vs baseline: 1.3578x; 1.0355x over previous
//
#include <hip/hip_runtime.h>
#include <math.h>

// ---------------------------------------------------------------------------
// GCN 2-layer: h1 = relu(gcnconv(x,W1,b1)); out = log_softmax(gcnconv(h1,W2,b2))
// R12 (resubmitted after audit; prior round was a GPU-acquisition timeout):
//  (a) h1/h1a rows stored PRE-SCALED by dinv[row] (applied in gemm1 epilogue /
//      agg<0> epilogue). Neighbor contribution becomes a plain add -> the
//      per-edge dinv[src] gathers (4 loads/lane/iter) are gone. Masked slots
//      read a sentinel zero row at index n (two 128B memsets).
//  (b) 2 nodes per wave (4 edge-groups x 8 feat-lanes, chunk-16): expected
//      gather slots/node 32 -> ~24 (Poisson(16)), wave count halved, epilogue
//      writes 2 bf16/lane (row = 32 lanes x 4B, coalesced).
// R11 counting-sort CSR build, R9 structure:
//   out = log_softmax( agg2(relu(agg1(x@W1)+b1)) @ W2 + b2 )
// gemm1/gemm2sm via bf16 MFMA (W2 split hi/lo bf16 for ~f32 accuracy).
// N=100000, E=1600000, F: 512 -> 64 -> 40
// ---------------------------------------------------------------------------

#define FIN 512
#define FHID 64
#define FOUT 40

#define BSH 8          // log2(nodes per bucket)
#define BN 256         // nodes per bucket
#define BCAP 5120      // staging capacity per bucket (mean 4096, +16 sigma)
#define EPW 4096       // edges per workgroup in B1

typedef __attribute__((ext_vector_type(8))) short short8;
typedef __attribute__((ext_vector_type(4))) float f32x4;
typedef unsigned short ushort_t;
typedef unsigned int uint_t;

__device__ __forceinline__ ushort_t bf16_rn(float f) {
    union { float f; uint_t u; } v; v.f = f;
    uint_t r = v.u + 0x7FFF + ((v.u >> 16) & 1);
    return (ushort_t)(r >> 16);
}
__device__ __forceinline__ uint_t pack_bf16(float a, float b) {
    return (uint_t)bf16_rn(a) | ((uint_t)bf16_rn(b) << 16);
}
__device__ __forceinline__ float bf16_to_f(ushort_t u) {
    union { uint_t i; float f; } t; t.i = ((uint_t)u) << 16; return t.f;
}
// accumulate 8 pre-scaled bf16 feats (one uint4) into acc[8]
__device__ __forceinline__ void add8(float* acc, uint4 g) {
    acc[0] += __uint_as_float(g.x << 16);
    acc[1] += __uint_as_float(g.x & 0xFFFF0000u);
    acc[2] += __uint_as_float(g.y << 16);
    acc[3] += __uint_as_float(g.y & 0xFFFF0000u);
    acc[4] += __uint_as_float(g.z << 16);
    acc[5] += __uint_as_float(g.z & 0xFFFF0000u);
    acc[6] += __uint_as_float(g.w << 16);
    acc[7] += __uint_as_float(g.w & 0xFFFF0000u);
}

// ---------------- B1: bucket scatter ----------------
__global__ __launch_bounds__(256) void bucket_scatter_kernel(
    const int* __restrict__ row, const int* __restrict__ col,
    int* __restrict__ gcur, uint_t* __restrict__ stage, int E) {
    __shared__ uint_t cnt[512];
    __shared__ uint_t base[512];
    int tid = threadIdx.x;
    cnt[tid] = 0; cnt[tid + 256] = 0;
    __syncthreads();
    int e0 = blockIdx.x * EPW;
    int creg[16];
#pragma unroll
    for (int it = 0; it < 16; ++it) {
        int e = e0 + it * 256 + tid;
        creg[it] = (e < E) ? col[e] : -1;
        if (e < E) atomicAdd(&cnt[((uint_t)creg[it]) >> BSH], 1u);
    }
    __syncthreads();
    uint_t c0 = cnt[tid], c1 = cnt[tid + 256];
    base[tid] = c0 ? (uint_t)atomicAdd(&gcur[tid], (int)c0) : 0u;
    base[tid + 256] = c1 ? (uint_t)atomicAdd(&gcur[tid + 256], (int)c1) : 0u;
    __syncthreads();
    cnt[tid] = 0; cnt[tid + 256] = 0;
    __syncthreads();
#pragma unroll
    for (int it = 0; it < 16; ++it) {
        int e = e0 + it * 256 + tid;
        if (e < E) {
            int c = creg[it];
            int r = row[e];
            int b = c >> BSH;
            uint_t slot = base[b] + atomicAdd(&cnt[b], 1u);
            stage[(size_t)b * BCAP + slot] = ((uint_t)r << BSH) | (uint_t)(c & (BN - 1));
        }
    }
}

// ---------------- scan (in-place exclusive, <=512 entries) ----------------
__global__ void scan2_kernel(int* __restrict__ bsums, int nb) {
    __shared__ int tmp[512];
    int tid = threadIdx.x;
    int v = (tid < nb) ? bsums[tid] : 0;
    tmp[tid] = v;
    __syncthreads();
    for (int off = 1; off < 512; off <<= 1) {
        int t = (tid >= off) ? tmp[tid - off] : 0;
        __syncthreads();
        tmp[tid] += t;
        __syncthreads();
    }
    if (tid < nb) bsums[tid] = tmp[tid] - v;
}

// ---------------- B2: per-bucket final placement + deg/dinv/offs ----------
__global__ __launch_bounds__(256) void bucket_place_kernel(
    const int* __restrict__ gcur, const uint_t* __restrict__ stage,
    int* __restrict__ sSrc, int* __restrict__ deg, float* __restrict__ dinv,
    int* __restrict__ offs, int n) {
    __shared__ int lcnt[256];
    __shared__ int ltmp[256];
    __shared__ int lpos[256];
    int b = blockIdx.x, tid = threadIdx.x;
    int nodeBase = b << BSH;
    int bucketBase = gcur[b];
    int cnt = gcur[b + 1] - bucketBase;
    lcnt[tid] = 0;
    __syncthreads();
    const uint_t* sp = &stage[(size_t)b * BCAP];
    for (int i = tid; i < cnt; i += 256)
        atomicAdd(&lcnt[sp[i] & (BN - 1)], 1);
    __syncthreads();
    int v = lcnt[tid];
    ltmp[tid] = v;
    __syncthreads();
    for (int off = 1; off < 256; off <<= 1) {
        int t = (tid >= off) ? ltmp[tid - off] : 0;
        __syncthreads();
        ltmp[tid] += t;
        __syncthreads();
    }
    int gofs = bucketBase + ltmp[tid] - v;   // global exclusive offset for node
    int node = nodeBase + tid;
    if (node < n) {
        deg[node] = v;
        dinv[node] = rsqrtf((float)v + 1.0f);
        offs[node] = gofs;
    }
    lpos[tid] = gofs;
    __syncthreads();
    for (int i = tid; i < cnt; i += 256) {
        uint_t w = sp[i];
        int pos = atomicAdd(&lpos[w & (BN - 1)], 1);
        sSrc[pos] = (int)(w >> BSH);
    }
}

// ---------------- weights prep: W1^T bf16 + W2^T hi/lo bf16 split ----------
__global__ void wprep_kernel(const float* __restrict__ W1, const float* __restrict__ W2,
                             ushort_t* __restrict__ Wt,
                             ushort_t* __restrict__ w2hi, ushort_t* __restrict__ w2lo) {
    int idx = blockIdx.x * 256 + threadIdx.x;   // 35840 = 32768 + 3072
    if (idx < 32768) {
        int nrow = idx >> 9;
        int k = idx & 511;
        Wt[idx] = bf16_rn(W1[k * 64 + nrow]);
    } else if (idx < 32768 + 3072) {
        int i = idx - 32768;
        int j = i >> 6, k = i & 63;
        float w = (j < FOUT) ? W2[k * FOUT + j] : 0.f;
        ushort_t h = bf16_rn(w);
        w2hi[i] = h;
        w2lo[i] = bf16_rn(w - bf16_to_f(h));
    }
}

// ---------------- GEMM1 (MFMA): h1b'[N,64] = bf16( (x@W1) * dinv[row] ) ----
// register-prefetch pipeline (single LDS buffer); PRE-SCALED epilogue.
#define LDA 72
#define LDB 72
__global__ __launch_bounds__(256) void gemm1_kernel(
    const float* __restrict__ x, const ushort_t* __restrict__ Wt,
    const float* __restrict__ dinv, ushort_t* __restrict__ h1b, int n) {
    __shared__ ushort_t lA[128 * LDA];
    __shared__ ushort_t lB[64 * LDB];

    int tid = threadIdx.x;
    int wave = tid >> 6, lane = tid & 63;
    int quad = lane >> 4, m16 = lane & 15;
    int node0 = blockIdx.x * 128;

    int r0 = tid >> 4, k4 = tid & 15;    // A: rows r0+16i, 16B at col k4*4
    int nr0 = tid >> 3, seg = tid & 7;   // B: rows nr0+32i, 16B at col seg*8

    f32x4 zero = {0.f, 0.f, 0.f, 0.f};
    f32x4 acc[2][4];
#pragma unroll
    for (int mt = 0; mt < 2; ++mt)
#pragma unroll
        for (int nt = 0; nt < 4; ++nt) acc[mt][nt] = zero;

    float4 ra[8];
    uint4 rb[2];

#pragma unroll
    for (int i = 0; i < 8; ++i) {
        int node = node0 + r0 + i * 16;
        float4 v = make_float4(0.f, 0.f, 0.f, 0.f);
        if (node < n) v = *reinterpret_cast<const float4*>(&x[(size_t)node * FIN + k4 * 4]);
        ra[i] = v;
    }
#pragma unroll
    for (int i = 0; i < 2; ++i)
        rb[i] = *reinterpret_cast<const uint4*>(&Wt[(size_t)(nr0 + i * 32) * FIN + seg * 8]);

    for (int c = 0; c < 8; ++c) {
#pragma unroll
        for (int i = 0; i < 8; ++i)
            *reinterpret_cast<uint2*>(&lA[(r0 + i * 16) * LDA + k4 * 4]) =
                make_uint2(pack_bf16(ra[i].x, ra[i].y), pack_bf16(ra[i].z, ra[i].w));
#pragma unroll
        for (int i = 0; i < 2; ++i)
            *reinterpret_cast<uint4*>(&lB[(nr0 + i * 32) * LDB + seg * 8]) = rb[i];
        __syncthreads();

        if (c < 7) {
            int kc = (c + 1) * 64;
#pragma unroll
            for (int i = 0; i < 8; ++i) {
                int node = node0 + r0 + i * 16;
                float4 v = make_float4(0.f, 0.f, 0.f, 0.f);
                if (node < n)
                    v = *reinterpret_cast<const float4*>(&x[(size_t)node * FIN + kc + k4 * 4]);
                ra[i] = v;
            }
#pragma unroll
            for (int i = 0; i < 2; ++i)
                rb[i] = *reinterpret_cast<const uint4*>(
                    &Wt[(size_t)(nr0 + i * 32) * FIN + kc + seg * 8]);
        }

#pragma unroll
        for (int kk = 0; kk < 2; ++kk) {
            short8 a[2], b[4];
#pragma unroll
            for (int mt = 0; mt < 2; ++mt)
                a[mt] = *reinterpret_cast<const short8*>(
                    &lA[(wave * 32 + mt * 16 + m16) * LDA + kk * 32 + quad * 8]);
#pragma unroll
            for (int nt = 0; nt < 4; ++nt)
                b[nt] = *reinterpret_cast<const short8*>(
                    &lB[(nt * 16 + m16) * LDB + kk * 32 + quad * 8]);
#pragma unroll
            for (int mt = 0; mt < 2; ++mt)
#pragma unroll
                for (int nt = 0; nt < 4; ++nt)
                    acc[mt][nt] = __builtin_amdgcn_mfma_f32_16x16x32_bf16(
                        a[mt], b[nt], acc[mt][nt], 0, 0, 0);
        }
        __syncthreads();
    }

#pragma unroll
    for (int mt = 0; mt < 2; ++mt) {
#pragma unroll
        for (int reg = 0; reg < 4; ++reg) {
            int node = node0 + wave * 32 + mt * 16 + quad * 4 + reg;
            if (node < n) {
                float di = dinv[node];
#pragma unroll
                for (int nt = 0; nt < 4; ++nt)
                    h1b[(size_t)node * 64 + nt * 16 + m16] =
                        bf16_rn(acc[mt][nt][reg] * di);
            }
        }
    }
}

// ---------------- pure aggregation kernel (templated, 2 nodes/wave) --------
// half-wave (32 lanes) = one node: 4 edge-groups x 8 feat-chunks x 16B
// gathers, chunk-16; src rows are PRE-SCALED by dinv[src]; masked slots read
// the sentinel zero row at index n. Cross-edge reduce via LDS transpose.
// MODE 0: dst = bf16(relu((sum+self)*di + b1) * di)   (pre-scaled for next agg)
// MODE 1: dst = bf16((sum+self)*di)                   (input to gemm2)
template <int MODE>
__global__ __launch_bounds__(256) void agg_kernel(
    const int* __restrict__ offs, const int* __restrict__ deg,
    const int* __restrict__ sSrc, const ushort_t* __restrict__ src,
    const float* __restrict__ dinv, const float* __restrict__ b1,
    ushort_t* __restrict__ dst, int n) {
    __shared__ float lacc[8][4 * 68];   // [node-slot][group*68 + feat]
    __shared__ float lb1[64];
    int tid = threadIdx.x;
    if (MODE == 0 && tid < 64) lb1[tid] = b1[tid];

    int wv = tid >> 6, lane = tid & 63;
    int half = lane >> 5;              // node within wave
    int l32 = lane & 31;
    int e4 = l32 >> 3, c = l32 & 7;    // edge-group, feat-chunk
    int slot = wv * 2 + half;          // 0..7
    int node = blockIdx.x * 8 + slot;
    bool valid = node < n;
    int start = valid ? offs[node] : 0;
    int cnt = valid ? deg[node] : 0;

    float acc[8];
#pragma unroll
    for (int j = 0; j < 8; ++j) acc[j] = 0.f;

    for (int base = 0; base < cnt; base += 16) {
        int i0 = base + e4, i1 = i0 + 4, i2 = i0 + 8, i3 = i0 + 12;
        int s0 = (i0 < cnt) ? sSrc[start + i0] : n;   // sentinel zero row
        int s1 = (i1 < cnt) ? sSrc[start + i1] : n;
        int s2 = (i2 < cnt) ? sSrc[start + i2] : n;
        int s3 = (i3 < cnt) ? sSrc[start + i3] : n;
        uint4 g0 = *reinterpret_cast<const uint4*>(&src[(size_t)s0 * 64 + c * 8]);
        uint4 g1 = *reinterpret_cast<const uint4*>(&src[(size_t)s1 * 64 + c * 8]);
        uint4 g2 = *reinterpret_cast<const uint4*>(&src[(size_t)s2 * 64 + c * 8]);
        uint4 g3 = *reinterpret_cast<const uint4*>(&src[(size_t)s3 * 64 + c * 8]);
        add8(acc, g0);
        add8(acc, g1);
        add8(acc, g2);
        add8(acc, g3);
    }

    // LDS transpose: lane (e4,c) -> lacc[slot][e4*68 + c*8 ..]
    {
        float* lw = &lacc[slot][e4 * 68 + c * 8];
        *reinterpret_cast<float4*>(lw) = make_float4(acc[0], acc[1], acc[2], acc[3]);
        *reinterpret_cast<float4*>(lw + 4) = make_float4(acc[4], acc[5], acc[6], acc[7]);
    }
    __syncthreads();

    // epilogue: thread t -> node-slot t>>5, feat-pair t&31 (2 feats)
    int s = tid >> 5;
    int fp = tid & 31;
    int enode = blockIdx.x * 8 + s;
    if (enode < n) {
        float sum0 = 0.f, sum1 = 0.f;
#pragma unroll
        for (int g = 0; g < 4; ++g) {
            sum0 += lacc[s][g * 68 + fp * 2];
            sum1 += lacc[s][g * 68 + fp * 2 + 1];
        }
        float di = dinv[enode];
        uint_t sv = *reinterpret_cast<const uint_t*>(&src[(size_t)enode * 64 + fp * 2]);
        float self0 = __uint_as_float(sv << 16);
        float self1 = __uint_as_float(sv & 0xFFFF0000u);
        float v0 = (sum0 + self0) * di;
        float v1 = (sum1 + self1) * di;
        if (MODE == 0) {
            v0 = fmaxf(v0 + lb1[fp * 2], 0.f) * di;
            v1 = fmaxf(v1 + lb1[fp * 2 + 1], 0.f) * di;
        }
        *reinterpret_cast<uint_t*>(&dst[(size_t)enode * 64 + fp * 2]) = pack_bf16(v0, v1);
    }
}

// ---------------- GEMM2 + bias + log_softmax (MFMA) ----------------
#define LDC 72
__global__ __launch_bounds__(256) void gemm2sm_kernel(
    const ushort_t* __restrict__ A, const ushort_t* __restrict__ w2hi,
    const ushort_t* __restrict__ w2lo, const float* __restrict__ b2,
    float* __restrict__ out, int n) {
    __shared__ ushort_t lA[128 * LDC];
    __shared__ ushort_t lBh[48 * LDC];
    __shared__ ushort_t lBl[48 * LDC];

    int tid = threadIdx.x;
    int wave = tid >> 6, lane = tid & 63;
    int quad = lane >> 4, m16 = lane & 15;
    int node0 = blockIdx.x * 128;

    {
        int r = tid & 127, part = tid >> 7;
        int node = node0 + r;
        uint4 z = make_uint4(0u, 0u, 0u, 0u);
        const uint4* sp = reinterpret_cast<const uint4*>(&A[(size_t)node * 64 + part * 32]);
#pragma unroll
        for (int i = 0; i < 4; ++i) {
            uint4 v = (node < n) ? sp[i] : z;
            *reinterpret_cast<uint4*>(&lA[r * LDC + part * 32 + i * 8]) = v;
        }
    }
    for (int i = tid; i < 384; i += 256) {
        int row = i >> 3, seg = i & 7;
        *reinterpret_cast<uint4*>(&lBh[row * LDC + seg * 8]) =
            reinterpret_cast<const uint4*>(w2hi)[i];
        *reinterpret_cast<uint4*>(&lBl[row * LDC + seg * 8]) =
            reinterpret_cast<const uint4*>(w2lo)[i];
    }
    float rb2_0 = b2[m16];
    float rb2_1 = b2[16 + m16];
    float rb2_2 = (m16 < 8) ? b2[32 + m16] : 0.f;
    __syncthreads();

    f32x4 zero = {0.f, 0.f, 0.f, 0.f};
    f32x4 acc[2][3];
#pragma unroll
    for (int mt = 0; mt < 2; ++mt)
#pragma unroll
        for (int nt = 0; nt < 3; ++nt) acc[mt][nt] = zero;

#pragma unroll
    for (int kk = 0; kk < 2; ++kk) {
        short8 a[2], bh[3], bl[3];
#pragma unroll
        for (int mt = 0; mt < 2; ++mt)
            a[mt] = *reinterpret_cast<const short8*>(
                &lA[(wave * 32 + mt * 16 + m16) * LDC + kk * 32 + quad * 8]);
#pragma unroll
        for (int nt = 0; nt < 3; ++nt) {
            bh[nt] = *reinterpret_cast<const short8*>(
                &lBh[(nt * 16 + m16) * LDC + kk * 32 + quad * 8]);
            bl[nt] = *reinterpret_cast<const short8*>(
                &lBl[(nt * 16 + m16) * LDC + kk * 32 + quad * 8]);
        }
#pragma unroll
        for (int mt = 0; mt < 2; ++mt)
#pragma unroll
            for (int nt = 0; nt < 3; ++nt) {
                acc[mt][nt] = __builtin_amdgcn_mfma_f32_16x16x32_bf16(
                    a[mt], bh[nt], acc[mt][nt], 0, 0, 0);
                acc[mt][nt] = __builtin_amdgcn_mfma_f32_16x16x32_bf16(
                    a[mt], bl[nt], acc[mt][nt], 0, 0, 0);
            }
    }

    bool c2 = (m16 < 8);
#pragma unroll
    for (int mt = 0; mt < 2; ++mt) {
#pragma unroll
        for (int reg = 0; reg < 4; ++reg) {
            int node = node0 + wave * 32 + mt * 16 + quad * 4 + reg;
            float r0 = acc[mt][0][reg] + rb2_0;
            float r1 = acc[mt][1][reg] + rb2_1;
            float r2 = acc[mt][2][reg] + rb2_2;
            float pm = fmaxf(fmaxf(r0, r1), c2 ? r2 : -INFINITY);
#pragma unroll
            for (int mask = 1; mask <= 8; mask <<= 1)
                pm = fmaxf(pm, __shfl_xor(pm, mask));
            float s = expf(r0 - pm) + expf(r1 - pm) + (c2 ? expf(r2 - pm) : 0.f);
#pragma unroll
            for (int mask = 1; mask <= 8; mask <<= 1)
                s += __shfl_xor(s, mask);
            float ls = logf(s) + pm;
            if (node < n) {
                float* op = &out[(size_t)node * FOUT];
                op[m16] = r0 - ls;
                op[16 + m16] = r1 - ls;
                if (c2) op[32 + m16] = r2 - ls;
            }
        }
    }
}

// ---------------------------------------------------------------------------
extern "C" void kernel_launch(void* const* d_in, const int* in_sizes, int n_in,
                              void* d_out, int out_size, void* d_ws, size_t ws_size,
                              hipStream_t stream) {
    const float* x  = (const float*)d_in[0];
    const int*   ei = (const int*)d_in[1];
    const float* W1 = (const float*)d_in[2];
    const float* b1 = (const float*)d_in[3];
    const float* W2 = (const float*)d_in[4];
    const float* b2 = (const float*)d_in[5];
    float* out = (float*)d_out;

    int n = in_sizes[0] / FIN;        // 100000
    int E = in_sizes[1] / 2;          // 1600000
    const int* row = ei;
    const int* col = ei + E;

    // workspace layout (4-byte words), ~44 MB total
    int* wsi = (int*)d_ws;
    const size_t NR = 100352;
    int*      deg   = wsi;                                  // [NR]
    float*    dinv  = (float*)(wsi + NR);                   // [NR]
    int*      offs  = wsi + 2 * NR;                         // [NR]
    int*      gcur  = wsi + 3 * NR;                         // [512] bucket cnt/base
    ushort_t* Wt    = (ushort_t*)(wsi + 3 * NR + 512);      // [64*512] bf16
    ushort_t* w2hi  = Wt + 64 * 512;                        // [48*64] bf16
    ushort_t* w2lo  = w2hi + 48 * 64;                       // [48*64] bf16
    uint_t*   stage = (uint_t*)(w2lo + 48 * 64);            // [512*BCAP]
    int*      sSrc  = (int*)(stage + (size_t)512 * BCAP);   // [E]
    ushort_t* h1b   = (ushort_t*)(sSrc + (size_t)E);        // [(n+1)*64] bf16
    ushort_t* h1a   = h1b + (size_t)(n + 1) * 64;           // [(n+1)*64] bf16
    ushort_t* Abuf  = h1b;                                  // reuse after agg<0>

    int NBUCK = (n + BN - 1) >> BSH;       // 391
    int nwg1 = (E + EPW - 1) / EPW;        // 391

    // ---- CSR build (two-level counting sort) + sentinel zero rows ----
    hipMemsetAsync(gcur, 0, 512 * 4, stream);
    hipMemsetAsync(h1b + (size_t)n * 64, 0, 128, stream);
    hipMemsetAsync(h1a + (size_t)n * 64, 0, 128, stream);
    bucket_scatter_kernel<<<nwg1, 256, 0, stream>>>(row, col, gcur, stage, E);
    scan2_kernel<<<1, 512, 0, stream>>>(gcur, 512);
    bucket_place_kernel<<<NBUCK, 256, 0, stream>>>(gcur, stage, sSrc, deg, dinv, offs, n);

    // ---- weights prep ----
    wprep_kernel<<<140, 256, 0, stream>>>(W1, W2, Wt, w2hi, w2lo);

    // ---- layer 1 transform (pre-scaled epilogue) ----
    gemm1_kernel<<<(n + 127) / 128, 256, 0, stream>>>(x, Wt, dinv, h1b, n);

    // ---- aggregation 1 (+bias+relu, pre-scaled out) -> h1a ----
    agg_kernel<0><<<(n + 7) / 8, 256, 0, stream>>>(offs, deg, sSrc, h1b, dinv, b1, h1a, n);

    // ---- aggregation 2 (pure) -> Abuf ----
    agg_kernel<1><<<(n + 7) / 8, 256, 0, stream>>>(offs, deg, sSrc, h1a, dinv, b1, Abuf, n);

    // ---- layer 2 transform + bias + log_softmax ----
    gemm2sm_kernel<<<(n + 127) / 128, 256, 0, stream>>>(Abuf, w2hi, w2lo, b2, out, n);
}

// Round 11
// 432.145 us; speedup vs baseline: 1.4010x; 1.0318x over previous
//
#include <hip/hip_runtime.h>
#include <math.h>

// ---------------------------------------------------------------------------
// GCN 2-layer: h1 = relu(gcnconv(x,W1,b1)); out = log_softmax(gcnconv(h1,W2,b2))
// R13 (resubmitted; prior three rounds were GPU-acquisition timeouts):
//  - memset x3 folded into wprep (zeros gcur + both sentinel rows), wprep first
//  - scan2 folded into bucket_place (per-block 512-entry LDS scan of raw
//    bucket counts) -> 11 graph nodes down to 7
//  - nontemporal loads on read-once streams (x, row/col, stage, sSrc, Abuf
//    staging) + nt stores for out: preserves per-XCD L2 for Wt/w2/gather tables
// R12: pre-scaled h1 rows (dinv folded at producer), sentinel zero row for
//      masked slots, 2 nodes/wave agg. R11: counting-sort CSR build.
// Structure: out = log_softmax( agg2(relu(agg1(x@W1)+b1)) @ W2 + b2 )
// N=100000, E=1600000, F: 512 -> 64 -> 40
// ---------------------------------------------------------------------------

#define FIN 512
#define FHID 64
#define FOUT 40

#define BSH 8          // log2(nodes per bucket)
#define BN 256         // nodes per bucket
#define BCAP 5120      // staging capacity per bucket (mean 4096, +16 sigma)
#define EPW 4096       // edges per workgroup in B1

typedef __attribute__((ext_vector_type(8))) short short8;
typedef __attribute__((ext_vector_type(4))) float f32x4;
typedef __attribute__((ext_vector_type(4))) float float4v;
typedef unsigned short ushort_t;
typedef unsigned int uint_t;
typedef __attribute__((ext_vector_type(4))) uint_t uint4v;

__device__ __forceinline__ ushort_t bf16_rn(float f) {
    union { float f; uint_t u; } v; v.f = f;
    uint_t r = v.u + 0x7FFF + ((v.u >> 16) & 1);
    return (ushort_t)(r >> 16);
}
__device__ __forceinline__ uint_t pack_bf16(float a, float b) {
    return (uint_t)bf16_rn(a) | ((uint_t)bf16_rn(b) << 16);
}
__device__ __forceinline__ float bf16_to_f(ushort_t u) {
    union { uint_t i; float f; } t; t.i = ((uint_t)u) << 16; return t.f;
}
// accumulate 8 pre-scaled bf16 feats (one uint4) into acc[8]
__device__ __forceinline__ void add8(float* acc, uint4 g) {
    acc[0] += __uint_as_float(g.x << 16);
    acc[1] += __uint_as_float(g.x & 0xFFFF0000u);
    acc[2] += __uint_as_float(g.y << 16);
    acc[3] += __uint_as_float(g.y & 0xFFFF0000u);
    acc[4] += __uint_as_float(g.z << 16);
    acc[5] += __uint_as_float(g.z & 0xFFFF0000u);
    acc[6] += __uint_as_float(g.w << 16);
    acc[7] += __uint_as_float(g.w & 0xFFFF0000u);
}

// ---------------- weights prep + init (memsets folded in) ----------------
// Wt: [64][512] bf16. w2hi/w2lo: [48][64] bf16 (rows 40..47 zero).
// Also zeroes gcur[512] and the two sentinel rows.
__global__ void wprep_kernel(const float* __restrict__ W1, const float* __restrict__ W2,
                             ushort_t* __restrict__ Wt,
                             ushort_t* __restrict__ w2hi, ushort_t* __restrict__ w2lo,
                             int* __restrict__ gcur,
                             ushort_t* __restrict__ sent1, ushort_t* __restrict__ sent2) {
    int idx = blockIdx.x * 256 + threadIdx.x;   // 35840 = 32768 + 3072
    if (idx < 512) gcur[idx] = 0;
    if (idx < 64) { sent1[idx] = 0; sent2[idx] = 0; }
    if (idx < 32768) {
        int nrow = idx >> 9;
        int k = idx & 511;
        Wt[idx] = bf16_rn(W1[k * 64 + nrow]);
    } else if (idx < 32768 + 3072) {
        int i = idx - 32768;
        int j = i >> 6, k = i & 63;
        float w = (j < FOUT) ? W2[k * FOUT + j] : 0.f;
        ushort_t h = bf16_rn(w);
        w2hi[i] = h;
        w2lo[i] = bf16_rn(w - bf16_to_f(h));
    }
}

// ---------------- B1: bucket scatter ----------------
__global__ __launch_bounds__(256) void bucket_scatter_kernel(
    const int* __restrict__ row, const int* __restrict__ col,
    int* __restrict__ gcur, uint_t* __restrict__ stage, int E) {
    __shared__ uint_t cnt[512];
    __shared__ uint_t base[512];
    int tid = threadIdx.x;
    cnt[tid] = 0; cnt[tid + 256] = 0;
    __syncthreads();
    int e0 = blockIdx.x * EPW;
    int creg[16];
#pragma unroll
    for (int it = 0; it < 16; ++it) {
        int e = e0 + it * 256 + tid;
        creg[it] = (e < E) ? __builtin_nontemporal_load(&col[e]) : -1;
        if (e < E) atomicAdd(&cnt[((uint_t)creg[it]) >> BSH], 1u);
    }
    __syncthreads();
    uint_t c0 = cnt[tid], c1 = cnt[tid + 256];
    base[tid] = c0 ? (uint_t)atomicAdd(&gcur[tid], (int)c0) : 0u;
    base[tid + 256] = c1 ? (uint_t)atomicAdd(&gcur[tid + 256], (int)c1) : 0u;
    __syncthreads();
    cnt[tid] = 0; cnt[tid + 256] = 0;
    __syncthreads();
#pragma unroll
    for (int it = 0; it < 16; ++it) {
        int e = e0 + it * 256 + tid;
        if (e < E) {
            int c = creg[it];
            int r = __builtin_nontemporal_load(&row[e]);
            int b = c >> BSH;
            uint_t slot = base[b] + atomicAdd(&cnt[b], 1u);
            stage[(size_t)b * BCAP + slot] = ((uint_t)r << BSH) | (uint_t)(c & (BN - 1));
        }
    }
}

// ---------------- B2: per-bucket placement + deg/dinv/offs (scan inlined) ---
__global__ __launch_bounds__(256) void bucket_place_kernel(
    const int* __restrict__ gcur, const uint_t* __restrict__ stage,
    int* __restrict__ sSrc, int* __restrict__ deg, float* __restrict__ dinv,
    int* __restrict__ offs, int n) {
    __shared__ int sc[512];
    __shared__ int lcnt[256];
    __shared__ int ltmp[256];
    __shared__ int lpos[256];
    int b = blockIdx.x, tid = threadIdx.x;
    int i1 = tid + 256;
    // inline exclusive scan of the 512 raw bucket counts (Hillis-Steele)
    sc[tid] = gcur[tid];
    sc[i1] = gcur[i1];
    __syncthreads();
    for (int off = 1; off < 512; off <<= 1) {
        int a0 = (tid >= off) ? sc[tid - off] : 0;
        int a1 = (i1 >= off) ? sc[i1 - off] : 0;
        __syncthreads();
        sc[tid] += a0; sc[i1] += a1;
        __syncthreads();
    }
    int cntB = gcur[b];                 // raw count of this bucket
    int bucketBase = sc[b] - cntB;      // exclusive prefix
    int nodeBase = b << BSH;
    lcnt[tid] = 0;
    __syncthreads();
    const uint_t* sp = &stage[(size_t)b * BCAP];
    for (int i = tid; i < cntB; i += 256)
        atomicAdd(&lcnt[__builtin_nontemporal_load(&sp[i]) & (BN - 1)], 1);
    __syncthreads();
    int v = lcnt[tid];
    ltmp[tid] = v;
    __syncthreads();
    for (int off = 1; off < 256; off <<= 1) {
        int t = (tid >= off) ? ltmp[tid - off] : 0;
        __syncthreads();
        ltmp[tid] += t;
        __syncthreads();
    }
    int gofs = bucketBase + ltmp[tid] - v;   // global exclusive offset for node
    int node = nodeBase + tid;
    if (node < n) {
        deg[node] = v;
        dinv[node] = rsqrtf((float)v + 1.0f);
        offs[node] = gofs;
    }
    lpos[tid] = gofs;
    __syncthreads();
    for (int i = tid; i < cntB; i += 256) {
        uint_t w = __builtin_nontemporal_load(&sp[i]);
        int pos = atomicAdd(&lpos[w & (BN - 1)], 1);
        sSrc[pos] = (int)(w >> BSH);
    }
}

// ---------------- GEMM1 (MFMA): h1b'[N,64] = bf16( (x@W1) * dinv[row] ) ----
// register-prefetch pipeline (single LDS buffer); PRE-SCALED epilogue.
// x loads nontemporal (read-once stream) so Wt stays L2-resident.
#define LDA 72
#define LDB 72
__global__ __launch_bounds__(256) void gemm1_kernel(
    const float* __restrict__ x, const ushort_t* __restrict__ Wt,
    const float* __restrict__ dinv, ushort_t* __restrict__ h1b, int n) {
    __shared__ ushort_t lA[128 * LDA];
    __shared__ ushort_t lB[64 * LDB];

    int tid = threadIdx.x;
    int wave = tid >> 6, lane = tid & 63;
    int quad = lane >> 4, m16 = lane & 15;
    int node0 = blockIdx.x * 128;

    int r0 = tid >> 4, k4 = tid & 15;    // A: rows r0+16i, 16B at col k4*4
    int nr0 = tid >> 3, seg = tid & 7;   // B: rows nr0+32i, 16B at col seg*8

    f32x4 zero = {0.f, 0.f, 0.f, 0.f};
    f32x4 acc[2][4];
#pragma unroll
    for (int mt = 0; mt < 2; ++mt)
#pragma unroll
        for (int nt = 0; nt < 4; ++nt) acc[mt][nt] = zero;

    float4v ra[8];
    uint4 rb[2];

#pragma unroll
    for (int i = 0; i < 8; ++i) {
        int node = node0 + r0 + i * 16;
        float4v v = {0.f, 0.f, 0.f, 0.f};
        if (node < n)
            v = __builtin_nontemporal_load(
                reinterpret_cast<const float4v*>(&x[(size_t)node * FIN + k4 * 4]));
        ra[i] = v;
    }
#pragma unroll
    for (int i = 0; i < 2; ++i)
        rb[i] = *reinterpret_cast<const uint4*>(&Wt[(size_t)(nr0 + i * 32) * FIN + seg * 8]);

    for (int c = 0; c < 8; ++c) {
#pragma unroll
        for (int i = 0; i < 8; ++i)
            *reinterpret_cast<uint2*>(&lA[(r0 + i * 16) * LDA + k4 * 4]) =
                make_uint2(pack_bf16(ra[i][0], ra[i][1]), pack_bf16(ra[i][2], ra[i][3]));
#pragma unroll
        for (int i = 0; i < 2; ++i)
            *reinterpret_cast<uint4*>(&lB[(nr0 + i * 32) * LDB + seg * 8]) = rb[i];
        __syncthreads();

        if (c < 7) {
            int kc = (c + 1) * 64;
#pragma unroll
            for (int i = 0; i < 8; ++i) {
                int node = node0 + r0 + i * 16;
                float4v v = {0.f, 0.f, 0.f, 0.f};
                if (node < n)
                    v = __builtin_nontemporal_load(
                        reinterpret_cast<const float4v*>(&x[(size_t)node * FIN + kc + k4 * 4]));
                ra[i] = v;
            }
#pragma unroll
            for (int i = 0; i < 2; ++i)
                rb[i] = *reinterpret_cast<const uint4*>(
                    &Wt[(size_t)(nr0 + i * 32) * FIN + kc + seg * 8]);
        }

#pragma unroll
        for (int kk = 0; kk < 2; ++kk) {
            short8 a[2], b[4];
#pragma unroll
            for (int mt = 0; mt < 2; ++mt)
                a[mt] = *reinterpret_cast<const short8*>(
                    &lA[(wave * 32 + mt * 16 + m16) * LDA + kk * 32 + quad * 8]);
#pragma unroll
            for (int nt = 0; nt < 4; ++nt)
                b[nt] = *reinterpret_cast<const short8*>(
                    &lB[(nt * 16 + m16) * LDB + kk * 32 + quad * 8]);
#pragma unroll
            for (int mt = 0; mt < 2; ++mt)
#pragma unroll
                for (int nt = 0; nt < 4; ++nt)
                    acc[mt][nt] = __builtin_amdgcn_mfma_f32_16x16x32_bf16(
                        a[mt], b[nt], acc[mt][nt], 0, 0, 0);
        }
        __syncthreads();
    }

#pragma unroll
    for (int mt = 0; mt < 2; ++mt) {
#pragma unroll
        for (int reg = 0; reg < 4; ++reg) {
            int node = node0 + wave * 32 + mt * 16 + quad * 4 + reg;
            if (node < n) {
                float di = dinv[node];
#pragma unroll
                for (int nt = 0; nt < 4; ++nt)
                    h1b[(size_t)node * 64 + nt * 16 + m16] =
                        bf16_rn(acc[mt][nt][reg] * di);
            }
        }
    }
}

// ---------------- pure aggregation kernel (templated, 2 nodes/wave) --------
// half-wave (32 lanes) = one node: 4 edge-groups x 8 feat-chunks x 16B
// gathers, chunk-16; src rows PRE-SCALED by dinv[src]; masked slots read the
// sentinel zero row at index n. sSrc loads nontemporal (read-once stream).
// MODE 0: dst = bf16(relu((sum+self)*di + b1) * di)   (pre-scaled for next agg)
// MODE 1: dst = bf16((sum+self)*di)                   (input to gemm2)
template <int MODE>
__global__ __launch_bounds__(256) void agg_kernel(
    const int* __restrict__ offs, const int* __restrict__ deg,
    const int* __restrict__ sSrc, const ushort_t* __restrict__ src,
    const float* __restrict__ dinv, const float* __restrict__ b1,
    ushort_t* __restrict__ dst, int n) {
    __shared__ float lacc[8][4 * 68];   // [node-slot][group*68 + feat]
    __shared__ float lb1[64];
    int tid = threadIdx.x;
    if (MODE == 0 && tid < 64) lb1[tid] = b1[tid];

    int wv = tid >> 6, lane = tid & 63;
    int half = lane >> 5;              // node within wave
    int l32 = lane & 31;
    int e4 = l32 >> 3, c = l32 & 7;    // edge-group, feat-chunk
    int slot = wv * 2 + half;          // 0..7
    int node = blockIdx.x * 8 + slot;
    bool valid = node < n;
    int start = valid ? offs[node] : 0;
    int cnt = valid ? deg[node] : 0;

    float acc[8];
#pragma unroll
    for (int j = 0; j < 8; ++j) acc[j] = 0.f;

    for (int base = 0; base < cnt; base += 16) {
        int i0 = base + e4, i1 = i0 + 4, i2 = i0 + 8, i3 = i0 + 12;
        int s0 = (i0 < cnt) ? __builtin_nontemporal_load(&sSrc[start + i0]) : n;
        int s1 = (i1 < cnt) ? __builtin_nontemporal_load(&sSrc[start + i1]) : n;
        int s2 = (i2 < cnt) ? __builtin_nontemporal_load(&sSrc[start + i2]) : n;
        int s3 = (i3 < cnt) ? __builtin_nontemporal_load(&sSrc[start + i3]) : n;
        uint4 g0 = *reinterpret_cast<const uint4*>(&src[(size_t)s0 * 64 + c * 8]);
        uint4 g1 = *reinterpret_cast<const uint4*>(&src[(size_t)s1 * 64 + c * 8]);
        uint4 g2 = *reinterpret_cast<const uint4*>(&src[(size_t)s2 * 64 + c * 8]);
        uint4 g3 = *reinterpret_cast<const uint4*>(&src[(size_t)s3 * 64 + c * 8]);
        add8(acc, g0);
        add8(acc, g1);
        add8(acc, g2);
        add8(acc, g3);
    }

    // LDS transpose: lane (e4,c) -> lacc[slot][e4*68 + c*8 ..]
    {
        float* lw = &lacc[slot][e4 * 68 + c * 8];
        *reinterpret_cast<float4*>(lw) = make_float4(acc[0], acc[1], acc[2], acc[3]);
        *reinterpret_cast<float4*>(lw + 4) = make_float4(acc[4], acc[5], acc[6], acc[7]);
    }
    __syncthreads();

    // epilogue: thread t -> node-slot t>>5, feat-pair t&31 (2 feats)
    int s = tid >> 5;
    int fp = tid & 31;
    int enode = blockIdx.x * 8 + s;
    if (enode < n) {
        float sum0 = 0.f, sum1 = 0.f;
#pragma unroll
        for (int g = 0; g < 4; ++g) {
            sum0 += lacc[s][g * 68 + fp * 2];
            sum1 += lacc[s][g * 68 + fp * 2 + 1];
        }
        float di = dinv[enode];
        uint_t sv = *reinterpret_cast<const uint_t*>(&src[(size_t)enode * 64 + fp * 2]);
        float self0 = __uint_as_float(sv << 16);
        float self1 = __uint_as_float(sv & 0xFFFF0000u);
        float v0 = (sum0 + self0) * di;
        float v1 = (sum1 + self1) * di;
        if (MODE == 0) {
            v0 = fmaxf(v0 + lb1[fp * 2], 0.f) * di;
            v1 = fmaxf(v1 + lb1[fp * 2 + 1], 0.f) * di;
        }
        *reinterpret_cast<uint_t*>(&dst[(size_t)enode * 64 + fp * 2]) = pack_bf16(v0, v1);
    }
}

// ---------------- GEMM2 + bias + log_softmax (MFMA) ----------------
#define LDC 72
__global__ __launch_bounds__(256) void gemm2sm_kernel(
    const ushort_t* __restrict__ A, const ushort_t* __restrict__ w2hi,
    const ushort_t* __restrict__ w2lo, const float* __restrict__ b2,
    float* __restrict__ out, int n) {
    __shared__ ushort_t lA[128 * LDC];
    __shared__ ushort_t lBh[48 * LDC];
    __shared__ ushort_t lBl[48 * LDC];

    int tid = threadIdx.x;
    int wave = tid >> 6, lane = tid & 63;
    int quad = lane >> 4, m16 = lane & 15;
    int node0 = blockIdx.x * 128;

    {
        int r = tid & 127, part = tid >> 7;
        int node = node0 + r;
        uint4v z = {0u, 0u, 0u, 0u};
        const uint4v* sp = reinterpret_cast<const uint4v*>(&A[(size_t)node * 64 + part * 32]);
#pragma unroll
        for (int i = 0; i < 4; ++i) {
            uint4v v = (node < n) ? __builtin_nontemporal_load(sp + i) : z;
            *reinterpret_cast<uint4v*>(&lA[r * LDC + part * 32 + i * 8]) = v;
        }
    }
    for (int i = tid; i < 384; i += 256) {
        int row = i >> 3, seg = i & 7;
        *reinterpret_cast<uint4*>(&lBh[row * LDC + seg * 8]) =
            reinterpret_cast<const uint4*>(w2hi)[i];
        *reinterpret_cast<uint4*>(&lBl[row * LDC + seg * 8]) =
            reinterpret_cast<const uint4*>(w2lo)[i];
    }
    float rb2_0 = b2[m16];
    float rb2_1 = b2[16 + m16];
    float rb2_2 = (m16 < 8) ? b2[32 + m16] : 0.f;
    __syncthreads();

    f32x4 zero = {0.f, 0.f, 0.f, 0.f};
    f32x4 acc[2][3];
#pragma unroll
    for (int mt = 0; mt < 2; ++mt)
#pragma unroll
        for (int nt = 0; nt < 3; ++nt) acc[mt][nt] = zero;

#pragma unroll
    for (int kk = 0; kk < 2; ++kk) {
        short8 a[2], bh[3], bl[3];
#pragma unroll
        for (int mt = 0; mt < 2; ++mt)
            a[mt] = *reinterpret_cast<const short8*>(
                &lA[(wave * 32 + mt * 16 + m16) * LDC + kk * 32 + quad * 8]);
#pragma unroll
        for (int nt = 0; nt < 3; ++nt) {
            bh[nt] = *reinterpret_cast<const short8*>(
                &lBh[(nt * 16 + m16) * LDC + kk * 32 + quad * 8]);
            bl[nt] = *reinterpret_cast<const short8*>(
                &lBl[(nt * 16 + m16) * LDC + kk * 32 + quad * 8]);
        }
#pragma unroll
        for (int mt = 0; mt < 2; ++mt)
#pragma unroll
            for (int nt = 0; nt < 3; ++nt) {
                acc[mt][nt] = __builtin_amdgcn_mfma_f32_16x16x32_bf16(
                    a[mt], bh[nt], acc[mt][nt], 0, 0, 0);
                acc[mt][nt] = __builtin_amdgcn_mfma_f32_16x16x32_bf16(
                    a[mt], bl[nt], acc[mt][nt], 0, 0, 0);
            }
    }

    bool c2 = (m16 < 8);
#pragma unroll
    for (int mt = 0; mt < 2; ++mt) {
#pragma unroll
        for (int reg = 0; reg < 4; ++reg) {
            int node = node0 + wave * 32 + mt * 16 + quad * 4 + reg;
            float r0 = acc[mt][0][reg] + rb2_0;
            float r1 = acc[mt][1][reg] + rb2_1;
            float r2 = acc[mt][2][reg] + rb2_2;
            float pm = fmaxf(fmaxf(r0, r1), c2 ? r2 : -INFINITY);
#pragma unroll
            for (int mask = 1; mask <= 8; mask <<= 1)
                pm = fmaxf(pm, __shfl_xor(pm, mask));
            float s = expf(r0 - pm) + expf(r1 - pm) + (c2 ? expf(r2 - pm) : 0.f);
#pragma unroll
            for (int mask = 1; mask <= 8; mask <<= 1)
                s += __shfl_xor(s, mask);
            float ls = logf(s) + pm;
            if (node < n) {
                float* op = &out[(size_t)node * FOUT];
                __builtin_nontemporal_store(r0 - ls, &op[m16]);
                __builtin_nontemporal_store(r1 - ls, &op[16 + m16]);
                if (c2) __builtin_nontemporal_store(r2 - ls, &op[32 + m16]);
            }
        }
    }
}

// ---------------------------------------------------------------------------
extern "C" void kernel_launch(void* const* d_in, const int* in_sizes, int n_in,
                              void* d_out, int out_size, void* d_ws, size_t ws_size,
                              hipStream_t stream) {
    const float* x  = (const float*)d_in[0];
    const int*   ei = (const int*)d_in[1];
    const float* W1 = (const float*)d_in[2];
    const float* b1 = (const float*)d_in[3];
    const float* W2 = (const float*)d_in[4];
    const float* b2 = (const float*)d_in[5];
    float* out = (float*)d_out;

    int n = in_sizes[0] / FIN;        // 100000
    int E = in_sizes[1] / 2;          // 1600000
    const int* row = ei;
    const int* col = ei + E;

    // workspace layout (4-byte words), ~44 MB total
    int* wsi = (int*)d_ws;
    const size_t NR = 100352;
    int*      deg   = wsi;                                  // [NR]
    float*    dinv  = (float*)(wsi + NR);                   // [NR]
    int*      offs  = wsi + 2 * NR;                         // [NR]
    int*      gcur  = wsi + 3 * NR;                         // [512] bucket counts
    ushort_t* Wt    = (ushort_t*)(wsi + 3 * NR + 512);      // [64*512] bf16
    ushort_t* w2hi  = Wt + 64 * 512;                        // [48*64] bf16
    ushort_t* w2lo  = w2hi + 48 * 64;                       // [48*64] bf16
    uint_t*   stage = (uint_t*)(w2lo + 48 * 64);            // [512*BCAP]
    int*      sSrc  = (int*)(stage + (size_t)512 * BCAP);   // [E]
    ushort_t* h1b   = (ushort_t*)(sSrc + (size_t)E);        // [(n+1)*64] bf16
    ushort_t* h1a   = h1b + (size_t)(n + 1) * 64;           // [(n+1)*64] bf16
    ushort_t* Abuf  = h1b;                                  // reuse after agg<0>

    int NBUCK = (n + BN - 1) >> BSH;       // 391
    int nwg1 = (E + EPW - 1) / EPW;        // 391

    // ---- weights prep + gcur/sentinel init (one kernel, runs first) ----
    wprep_kernel<<<140, 256, 0, stream>>>(W1, W2, Wt, w2hi, w2lo, gcur,
                                          h1b + (size_t)n * 64, h1a + (size_t)n * 64);

    // ---- CSR build (two-level counting sort; scan inlined in B2) ----
    bucket_scatter_kernel<<<nwg1, 256, 0, stream>>>(row, col, gcur, stage, E);
    bucket_place_kernel<<<NBUCK, 256, 0, stream>>>(gcur, stage, sSrc, deg, dinv, offs, n);

    // ---- layer 1 transform (pre-scaled epilogue) ----
    gemm1_kernel<<<(n + 127) / 128, 256, 0, stream>>>(x, Wt, dinv, h1b, n);

    // ---- aggregation 1 (+bias+relu, pre-scaled out) -> h1a ----
    agg_kernel<0><<<(n + 7) / 8, 256, 0, stream>>>(offs, deg, sSrc, h1b, dinv, b1, h1a, n);

    // ---- aggregation 2 (pure) -> Abuf ----
    agg_kernel<1><<<(n + 7) / 8, 256, 0, stream>>>(offs, deg, sSrc, h1a, dinv, b1, Abuf, n);

    // ---- layer 2 transform + bias + log_softmax ----
    gemm2sm_kernel<<<(n + 127) / 128, 256, 0, stream>>>(Abuf, w2hi, w2lo, b2, out, n);
}